// Round 4
// baseline (522.143 us; speedup 1.0000x reference)
//
#include <hip/hip_runtime.h>
#include <hip/hip_bf16.h>

// Problem constants (match reference)
constexpr int NE  = 8;     // experts
constexpr int T   = 2048;  // tokens
constexpr int IN  = 2048;  // reduction dim
constexpr int OUT = 2048;  // output dim
constexpr int GS  = 64;    // quant group size
constexpr int G   = IN / GS;

// Tile config
constexpr int BM = 128;
constexpr int BN = 64;
constexpr int BK = 64;            // == GS: one scale/zero per K-tile
constexpr int NTILE = IN / BK;    // 32
constexpr int LDB = 64;           // no pad: XOR swizzle handles banks

using short8  = __attribute__((ext_vector_type(8))) short;
using short4v = __attribute__((ext_vector_type(4))) short;
using floatx4 = __attribute__((ext_vector_type(4))) float;
using int4v   = __attribute__((ext_vector_type(4))) int;
using float4v = __attribute__((ext_vector_type(4))) float;

// x fp32 -> bf16 pre-pass (x is the GEMM A operand)
__global__ __launch_bounds__(256)
void cvt_x_bf16(const float* __restrict__ x, __hip_bfloat16* __restrict__ xb) {
    const int i = (blockIdx.x * 256 + threadIdx.x) * 4;
    const float4 v = *(const float4*)(x + i);
    union { unsigned long long u; __hip_bfloat162 h2[2]; } p;
    p.h2[0] = __float22bfloat162_rn(float2{v.x, v.y});
    p.h2[1] = __float22bfloat162_rn(float2{v.z, v.w});
    *(unsigned long long*)(xb + i) = p.u;
}

__global__ __launch_bounds__(256, 3)
void hqq_grouped_gemm(const __hip_bfloat16* __restrict__ xb,
                      const int*   __restrict__ qw,
                      const float* __restrict__ snz,   // [E][G][OUT][2]
                      const int*   __restrict__ tpe,   // [E]
                      float* __restrict__ out) {
    const int tid = threadIdx.x;
    // tm FASTEST (blockIdx.x): active blocks (tm < tiles(e)) are short runs
    // every T/BM dispatches -> in-order dispatcher spreads them over all CUs.
    // (r2 had n0 fastest: 32-long active bursts -> ~32 CUs busy, rest idle.)
    const int tm  = blockIdx.x;
    const int n0  = blockIdx.y * BN;
    const int e   = blockIdx.z;

    // expert row bounds from prefix sum (wave-uniform, L2-hot)
    int b0 = 0;
#pragma unroll
    for (int i = 0; i < NE; ++i) { int c = tpe[i]; if (i < e) b0 += c; }
    const int b1 = b0 + tpe[e];
    const int row0 = b0 + tm * BM;
    if (row0 >= b1) return;

    // Double-buffered B tile, XOR-swizzled (k ^= ((row>>2)&3)<<4 shorts).
    __shared__ __hip_bfloat16 Bs[2][BN][LDB];

    floatx4 acc[2][4];
#pragma unroll
    for (int i = 0; i < 2; ++i)
#pragma unroll
        for (int j = 0; j < 4; ++j)
            acc[i][j] = (floatx4){0.f, 0.f, 0.f, 0.f};

    // B-stage mapping: 4 consecutive n (dwordx4) x 4 consecutive k per thread
    const int n4  = (tid & 15) * 4;   // 16 n-groups cover BN=64
    const int kq4 = (tid >> 4) * 4;   // 16 k-groups cover BK=64
    const int wsz = (tid & 3) << 4;   // write swizzle: ((row>>2)&3)<<4, row=n4+nn -> tid&3

    // MFMA decomposition: 4 waves stacked in m (32 rows each)
    const int lane = tid & 63;
    const int wid  = tid >> 6;
    const int wm = wid * 32;
    const int lm = lane & 15;
    const int lk = (lane >> 4) * 8;
    const int rsz = ((lm >> 2) & 3) << 4;  // read swizzle: same row-function (rows j*16+lm)

    const int*    qbase  = qw + (size_t)e * IN * OUT + n0 + n4;
    const float2* szbase = (const float2*)snz + (size_t)e * G * OUT + n0 + n4;

    // A-fragment row pointers (clamped once; garbage rows never stored)
    const int r0c = min(row0 + wm + lm,      b1 - 1);
    const int r1c = min(row0 + wm + 16 + lm, b1 - 1);
    const __hip_bfloat16* ap0 = xb + (size_t)r0c * IN + lk;
    const __hip_bfloat16* ap1 = xb + (size_t)r1c * IN + lk;

    // ---- register prefetch state (named A/B sets, no runtime indexing) ----
    int4v   qvA[4], qvB[4];
    float4v szA[2], szB[2];
    short8  afA[4], afB[4];   // [ks2*2+i]: 2 k-halves x 2 row-groups

    auto issue_q = [&](int t, int4v (&qv)[4], float4v (&sz)[2]) {
        const int k0 = t * BK;
        const float4v* szp = (const float4v*)(szbase + (size_t)(k0 >> 6) * OUT);
        sz[0] = szp[0];
        sz[1] = szp[1];
#pragma unroll
        for (int kk = 0; kk < 4; ++kk)
            qv[kk] = *(const int4v*)(qbase + (size_t)(k0 + kq4 + kk) * OUT);
    };

    auto issue_af = [&](int t, short8 (&af)[4]) {
        const int k0 = t * BK;
        af[0] = *(const short8*)(ap0 + k0);
        af[1] = *(const short8*)(ap1 + k0);
        af[2] = *(const short8*)(ap0 + k0 + 32);
        af[3] = *(const short8*)(ap1 + k0 + 32);
    };

    // dequant 4x4 (k x n) micro-tile from regs -> LDS (4x ds_write_b64, swizzled)
    auto stage = [&](__hip_bfloat16 (&B)[BN][LDB], int4v (&qv)[4], float4v (&sz)[2]) {
#pragma unroll
        for (int nn = 0; nn < 4; ++nn) {
            const float sc = sz[nn >> 1][(nn & 1) * 2];
            const float cc = sz[nn >> 1][(nn & 1) * 2 + 1] - 8.0f * sc;  // (q-8)*s+z == q*s+cc
            union { short4v v; __hip_bfloat162 h2[2]; } pb;
            pb.h2[0] = __float22bfloat162_rn(float2{(float)qv[0][nn] * sc + cc,
                                                    (float)qv[1][nn] * sc + cc});
            pb.h2[1] = __float22bfloat162_rn(float2{(float)qv[2][nn] * sc + cc,
                                                    (float)qv[3][nn] * sc + cc});
            *(short4v*)&B[n4 + nn][kq4 ^ wsz] = pb.v;
        }
    };

    // MFMA over one K-tile; A-frags from prefetched registers (no vmem waits)
    auto mfma_tile = [&](const __hip_bfloat16 (&B)[BN][LDB], const short8 (&af)[4]) {
#pragma unroll
        for (int ks2 = 0; ks2 < 2; ++ks2) {
            short8 bfr[4];
#pragma unroll
            for (int j = 0; j < 4; ++j)
                bfr[j] = *(const short8*)&B[j * 16 + lm][(ks2 * 32 + lk) ^ rsz];
#pragma unroll
            for (int i = 0; i < 2; ++i)
#pragma unroll
                for (int j = 0; j < 4; ++j)
                    acc[i][j] = __builtin_amdgcn_mfma_f32_16x16x32_bf16(
                        af[ks2 * 2 + i], bfr[j], acc[i][j], 0, 0, 0);
        }
    };

    // Raw barrier: lgkm drain for LDS visibility; register prefetch loads
    // (vmcnt) legally stay in flight across it. sched_barrier(0) prevents
    // LDS ops from being scheduled across the barrier.
#define TILE_SYNC()                                          \
    asm volatile("s_waitcnt lgkmcnt(0)" ::: "memory");       \
    __builtin_amdgcn_s_barrier();                            \
    __builtin_amdgcn_sched_barrier(0)

    issue_q(0, qvA, szA);
    issue_q(1, qvB, szB);
    issue_af(0, afA);
    issue_af(1, afB);

    for (int t = 0; t < NTILE; t += 2) {
        // even tile -> buf0 (set A); reissue A for t+2 (2-tile window)
        stage(Bs[0], qvA, szA);
        { const int tn = (t + 2 < NTILE) ? t + 2 : NTILE - 1; issue_q(tn, qvA, szA); }
        TILE_SYNC();
        mfma_tile(Bs[0], afA);
        { const int tn = (t + 2 < NTILE) ? t + 2 : NTILE - 1; issue_af(tn, afA); }

        // odd tile -> buf1 (set B); reissue B for t+3
        stage(Bs[1], qvB, szB);
        { const int tn = (t + 3 < NTILE) ? t + 3 : NTILE - 1; issue_q(tn, qvB, szB); }
        TILE_SYNC();
        mfma_tile(Bs[1], afB);
        { const int tn = (t + 3 < NTILE) ? t + 3 : NTILE - 1; issue_af(tn, afB); }
    }
#undef TILE_SYNC

    // ---- epilogue: plain stores. C/D layout col=lane&15, row=(lane>>4)*4+reg ----
    const int lq = (lane >> 4) * 4;
#pragma unroll
    for (int i = 0; i < 2; ++i) {
#pragma unroll
        for (int r = 0; r < 4; ++r) {
            const int row = row0 + wm + i * 16 + lq + r;
            if (row < b1) {
                float* op = out + (size_t)row * OUT + n0 + lm;
#pragma unroll
                for (int j = 0; j < 4; ++j)
                    op[j * 16] = acc[i][j][r];
            }
        }
    }
}

extern "C" void kernel_launch(void* const* d_in, const int* in_sizes, int n_in,
                              void* d_out, int out_size, void* d_ws, size_t ws_size,
                              hipStream_t stream) {
    const float* x   = (const float*)d_in[0];
    const int*   qw  = (const int*)d_in[1];
    const float* snz = (const float*)d_in[2];
    const int*   tpe = (const int*)d_in[3];
    float* out = (float*)d_out;
    __hip_bfloat16* xb = (__hip_bfloat16*)d_ws;   // needs T*IN*2 = 8.4 MB of ws

    cvt_x_bf16<<<(T * IN) / (256 * 4), 256, 0, stream>>>(x, xb);

    // every output row belongs to exactly one expert tile -> full coverage,
    // plain stores overwrite the poison; no memset, no atomics
    dim3 grid(T / BM, OUT / BN, NE);   // x=tm (fastest), y=n0, z=e
    hqq_grouped_gemm<<<grid, 256, 0, stream>>>(xb, qw, snz, tpe, out);
}

// Round 5
// 247.998 us; speedup vs baseline: 2.1054x; 2.1054x over previous
//
#include <hip/hip_runtime.h>
#include <hip/hip_bf16.h>

// Problem constants (match reference)
constexpr int NE  = 8;     // experts
constexpr int T   = 2048;  // tokens
constexpr int IN  = 2048;  // reduction dim
constexpr int OUT = 2048;  // output dim
constexpr int GS  = 64;    // quant group size
constexpr int G   = IN / GS;

// Tile config
constexpr int BM = 128;
constexpr int BN = 64;
constexpr int BK = 64;            // == GS: one scale/zero per K-tile
constexpr int NTILE = IN / BK;    // 32
constexpr int LDB = 64;           // no pad: XOR swizzle handles banks
// Max total active M-tiles: sum_e ceil(tpe[e]/BM) <= T/BM + (NE-1) = 23; pad to 24
constexpr int MAXMT = T / BM + NE;

using short8  = __attribute__((ext_vector_type(8))) short;
using short4v = __attribute__((ext_vector_type(4))) short;
using floatx4 = __attribute__((ext_vector_type(4))) float;
using int4v   = __attribute__((ext_vector_type(4))) int;
using float4v = __attribute__((ext_vector_type(4))) float;

// x fp32 -> bf16 pre-pass (x is the GEMM A operand)
__global__ __launch_bounds__(256)
void cvt_x_bf16(const float* __restrict__ x, __hip_bfloat16* __restrict__ xb) {
    const int i = (blockIdx.x * 256 + threadIdx.x) * 4;
    const float4 v = *(const float4*)(x + i);
    union { unsigned long long u; __hip_bfloat162 h2[2]; } p;
    p.h2[0] = __float22bfloat162_rn(float2{v.x, v.y});
    p.h2[1] = __float22bfloat162_rn(float2{v.z, v.w});
    *(unsigned long long*)(xb + i) = p.u;
}

__global__ __launch_bounds__(256, 3)
void hqq_grouped_gemm(const __hip_bfloat16* __restrict__ xb,
                      const int*   __restrict__ qw,
                      const float* __restrict__ snz,   // [E][G][OUT][2]
                      const int*   __restrict__ tpe,   // [E]
                      float* __restrict__ out) {
    const int tid = threadIdx.x;
    const int n0  = blockIdx.x * BN;

    // ---- COMPACT GRID: map mt slot -> (expert, m-tile) by walking tpe.
    // Dead blocks were the killer: 4096-block grid with ~640 active inherited
    // pathological CU/XCD placement (r2: 32-long bursts; r4: tm%8 XCD pileup).
    // Here all ~736 blocks are active and the whole problem is co-resident.
    const int mt = blockIdx.y;
    int e = -1, b0 = 0, b1 = 0, tm = 0;
    {
        int base = 0, rem = mt;
#pragma unroll
        for (int i = 0; i < NE; ++i) {
            const int c  = tpe[i];
            const int nt = (c + BM - 1) >> 7;   // ceil(c/128)
            if (e < 0) {
                if (rem < nt) { e = i; b0 = base; b1 = base + c; tm = rem; }
                else rem -= nt;
            }
            base += c;
        }
    }
    if (e < 0) return;   // mt beyond total active tiles (<= 1 slot per n0)
    const int row0 = b0 + tm * BM;

    // Double-buffered B tile, XOR-swizzled (k ^= ((row>>2)&3)<<4 shorts).
    __shared__ __hip_bfloat16 Bs[2][BN][LDB];

    floatx4 acc[2][4];
#pragma unroll
    for (int i = 0; i < 2; ++i)
#pragma unroll
        for (int j = 0; j < 4; ++j)
            acc[i][j] = (floatx4){0.f, 0.f, 0.f, 0.f};

    // B-stage mapping: 4 consecutive n (dwordx4) x 4 consecutive k per thread
    const int n4  = (tid & 15) * 4;   // 16 n-groups cover BN=64
    const int kq4 = (tid >> 4) * 4;   // 16 k-groups cover BK=64
    const int wsz = (tid & 3) << 4;   // write swizzle: ((row>>2)&3)<<4, row=n4+nn -> tid&3

    // MFMA decomposition: 4 waves stacked in m (32 rows each)
    const int lane = tid & 63;
    const int wid  = tid >> 6;
    const int wm = wid * 32;
    const int lm = lane & 15;
    const int lk = (lane >> 4) * 8;
    const int rsz = ((lm >> 2) & 3) << 4;  // read swizzle: same row-function (rows j*16+lm)

    const int*    qbase  = qw + (size_t)e * IN * OUT + n0 + n4;
    const float2* szbase = (const float2*)snz + (size_t)e * G * OUT + n0 + n4;

    // A-fragment row pointers (clamped once; garbage rows never stored)
    const int r0c = min(row0 + wm + lm,      b1 - 1);
    const int r1c = min(row0 + wm + 16 + lm, b1 - 1);
    const __hip_bfloat16* ap0 = xb + (size_t)r0c * IN + lk;
    const __hip_bfloat16* ap1 = xb + (size_t)r1c * IN + lk;

    // ---- register prefetch state (named A/B sets, no runtime indexing) ----
    int4v   qvA[4], qvB[4];
    float4v szA[2], szB[2];
    short8  afA[4], afB[4];   // [ks2*2+i]: 2 k-halves x 2 row-groups

    auto issue_q = [&](int t, int4v (&qv)[4], float4v (&sz)[2]) {
        const int k0 = t * BK;
        const float4v* szp = (const float4v*)(szbase + (size_t)(k0 >> 6) * OUT);
        sz[0] = szp[0];
        sz[1] = szp[1];
#pragma unroll
        for (int kk = 0; kk < 4; ++kk)
            qv[kk] = *(const int4v*)(qbase + (size_t)(k0 + kq4 + kk) * OUT);
    };

    auto issue_af = [&](int t, short8 (&af)[4]) {
        const int k0 = t * BK;
        af[0] = *(const short8*)(ap0 + k0);
        af[1] = *(const short8*)(ap1 + k0);
        af[2] = *(const short8*)(ap0 + k0 + 32);
        af[3] = *(const short8*)(ap1 + k0 + 32);
    };

    // dequant 4x4 (k x n) micro-tile from regs -> LDS (4x ds_write_b64, swizzled)
    auto stage = [&](__hip_bfloat16 (&B)[BN][LDB], int4v (&qv)[4], float4v (&sz)[2]) {
#pragma unroll
        for (int nn = 0; nn < 4; ++nn) {
            const float sc = sz[nn >> 1][(nn & 1) * 2];
            const float cc = sz[nn >> 1][(nn & 1) * 2 + 1] - 8.0f * sc;  // (q-8)*s+z == q*s+cc
            union { short4v v; __hip_bfloat162 h2[2]; } pb;
            pb.h2[0] = __float22bfloat162_rn(float2{(float)qv[0][nn] * sc + cc,
                                                    (float)qv[1][nn] * sc + cc});
            pb.h2[1] = __float22bfloat162_rn(float2{(float)qv[2][nn] * sc + cc,
                                                    (float)qv[3][nn] * sc + cc});
            *(short4v*)&B[n4 + nn][kq4 ^ wsz] = pb.v;
        }
    };

    // MFMA over one K-tile; A-frags from prefetched registers (no vmem waits)
    auto mfma_tile = [&](const __hip_bfloat16 (&B)[BN][LDB], const short8 (&af)[4]) {
#pragma unroll
        for (int ks2 = 0; ks2 < 2; ++ks2) {
            short8 bfr[4];
#pragma unroll
            for (int j = 0; j < 4; ++j)
                bfr[j] = *(const short8*)&B[j * 16 + lm][(ks2 * 32 + lk) ^ rsz];
#pragma unroll
            for (int i = 0; i < 2; ++i)
#pragma unroll
                for (int j = 0; j < 4; ++j)
                    acc[i][j] = __builtin_amdgcn_mfma_f32_16x16x32_bf16(
                        af[ks2 * 2 + i], bfr[j], acc[i][j], 0, 0, 0);
        }
    };

    // Raw barrier: lgkm drain for LDS visibility; register prefetch loads
    // (vmcnt) legally stay in flight across it. sched_barrier(0) prevents
    // LDS ops from being scheduled across the barrier.
#define TILE_SYNC()                                          \
    asm volatile("s_waitcnt lgkmcnt(0)" ::: "memory");       \
    __builtin_amdgcn_s_barrier();                            \
    __builtin_amdgcn_sched_barrier(0)

    issue_q(0, qvA, szA);
    issue_q(1, qvB, szB);
    issue_af(0, afA);
    issue_af(1, afB);

    for (int t = 0; t < NTILE; t += 2) {
        // even tile -> buf0 (set A); reissue A for t+2 (2-tile window)
        stage(Bs[0], qvA, szA);
        { const int tn = (t + 2 < NTILE) ? t + 2 : NTILE - 1; issue_q(tn, qvA, szA); }
        TILE_SYNC();
        mfma_tile(Bs[0], afA);
        { const int tn = (t + 2 < NTILE) ? t + 2 : NTILE - 1; issue_af(tn, afA); }

        // odd tile -> buf1 (set B); reissue B for t+3
        stage(Bs[1], qvB, szB);
        { const int tn = (t + 3 < NTILE) ? t + 3 : NTILE - 1; issue_q(tn, qvB, szB); }
        TILE_SYNC();
        mfma_tile(Bs[1], afB);
        { const int tn = (t + 3 < NTILE) ? t + 3 : NTILE - 1; issue_af(tn, afB); }
    }
#undef TILE_SYNC

    // ---- epilogue: plain stores. C/D layout col=lane&15, row=(lane>>4)*4+reg ----
    const int lq = (lane >> 4) * 4;
#pragma unroll
    for (int i = 0; i < 2; ++i) {
#pragma unroll
        for (int r = 0; r < 4; ++r) {
            const int row = row0 + wm + i * 16 + lq + r;
            if (row < b1) {
                float* op = out + (size_t)row * OUT + n0 + lm;
#pragma unroll
                for (int j = 0; j < 4; ++j)
                    op[j * 16] = acc[i][j][r];
            }
        }
    }
}

extern "C" void kernel_launch(void* const* d_in, const int* in_sizes, int n_in,
                              void* d_out, int out_size, void* d_ws, size_t ws_size,
                              hipStream_t stream) {
    const float* x   = (const float*)d_in[0];
    const int*   qw  = (const int*)d_in[1];
    const float* snz = (const float*)d_in[2];
    const int*   tpe = (const int*)d_in[3];
    float* out = (float*)d_out;
    __hip_bfloat16* xb = (__hip_bfloat16*)d_ws;   // needs T*IN*2 = 8.4 MB of ws

    cvt_x_bf16<<<(T * IN) / (256 * 4), 256, 0, stream>>>(x, xb);

    // Compact grid: every output row covered exactly once (mt slots walk the
    // per-expert tile counts in-kernel); plain stores overwrite the poison.
    dim3 grid(OUT / BN, MAXMT, 1);   // 32 x 24, ~96% active
    hqq_grouped_gemm<<<grid, 256, 0, stream>>>(xb, qw, snz, tpe, out);
}